// Round 4
// baseline (1995.143 us; speedup 1.0000x reference)
//
#include <hip/hip_runtime.h>
#include <math.h>

#define NN 50000
#define EE 800000
#define TT 6

__device__ __forceinline__ float lrelu(float x){ return x > 0.f ? x : 0.2f*x; }
__device__ __forceinline__ float eluf(float x){ return x > 0.f ? x : expm1f(x); }

#define RL(v,i) __uint_as_float(__builtin_amdgcn_readlane(__float_as_uint(v), (i)))

// ---------------- CSR build ----------------
__global__ void k_init_counts(int* __restrict__ c){
  int i = blockIdx.x*256 + threadIdx.x;
  if (i < NN) c[i] = 1;
}

__global__ void k_hist(const int* __restrict__ dst, int* __restrict__ c){
  int i = blockIdx.x*256 + threadIdx.x;
  if (i < EE) atomicAdd(&c[dst[i]], 1);
}

__global__ void k_scanA(const int* __restrict__ cnt, int* __restrict__ excl,
                        int* __restrict__ bsum){
  __shared__ int sh[1024];
  int tid = threadIdx.x;
  int i = blockIdx.x*1024 + tid;
  int v = (i < NN) ? cnt[i] : 0;
  int x = v;
  sh[tid] = x; __syncthreads();
  for (int off = 1; off < 1024; off <<= 1){
    int y = (tid >= off) ? sh[tid - off] : 0;
    __syncthreads();
    x += y; sh[tid] = x; __syncthreads();
  }
  if (i < NN) excl[i] = x - v;
  if (tid == 1023) bsum[blockIdx.x] = x;
}

__global__ void k_scanB(int* __restrict__ bsum, int nb){
  if (threadIdx.x == 0){
    int run = 0;
    for (int b = 0; b < nb; ++b){ int t = bsum[b]; bsum[b] = run; run += t; }
  }
}

__global__ void k_scanC(const int* __restrict__ excl, const int* __restrict__ bsum,
                        int* __restrict__ rowptr, int* __restrict__ cursor){
  int i = blockIdx.x*1024 + threadIdx.x;
  if (i < NN){
    int v = excl[i] + bsum[blockIdx.x];
    rowptr[i] = v; cursor[i] = v;
  }
  if (i == 0) rowptr[NN] = EE + NN;
}

__global__ void k_scatter(const int* __restrict__ ei, int* __restrict__ cursor,
                          int* __restrict__ csr){
  int i = blockIdx.x*256 + threadIdx.x;
  if (i < EE){
    int d = ei[EE + i];
    int p = atomicAdd(&cursor[d], 1);
    csr[p] = ei[i];
  } else if (i < EE + NN){
    int v = i - EE;
    int p = atomicAdd(&cursor[v], 1);
    csr[p] = v;
  }
}

// ---------------- weight preprocessing ----------------
// Wat[k][j]: j=0..3 -> src head j ; j=4..7 -> dst head j-4
__global__ void k_prep(const float* __restrict__ W1, const float* __restrict__ as1,
                       const float* __restrict__ ad1,
                       const float* __restrict__ W2, const float* __restrict__ as2,
                       const float* __restrict__ ad2,
                       const float* __restrict__ cw1, const float* __restrict__ cw2,
                       float* __restrict__ Wat1, float* __restrict__ Wat2,
                       float4* __restrict__ w1p, float4* __restrict__ w2p){
  int tid = threadIdx.x;          // 256
  int k = tid >> 2, h = tid & 3;
  float s1 = 0.f, d1 = 0.f, s2 = 0.f, d2 = 0.f;
  for (int c = 0; c < 16; ++c){
    float w = W1[k*64 + h*16 + c];
    s1 += w * as1[h*16 + c];
    d1 += w * ad1[h*16 + c];
  }
  for (int c = 0; c < 64; ++c){
    float w = W2[k*256 + h*64 + c];
    s2 += w * as2[h*64 + c];
    d2 += w * ad2[h*64 + c];
  }
  Wat1[k*8 + h] = s1; Wat1[k*8 + 4 + h] = d1;
  Wat2[k*8 + h] = s2; Wat2[k*8 + 4 + h] = d2;
  for (int idx = tid; idx < 64*64; idx += 256){
    int o = idx & 63, i = idx >> 6;
    w1p[idx] = make_float4(cw1[o*192+i*3], cw1[o*192+i*3+1], cw1[o*192+i*3+2], 0.f);
    w2p[idx] = make_float4(cw2[o*192+i*3], cw2[o*192+i*3+1], cw2[o*192+i*3+2], 0.f);
  }
}

// ---------------- GEMM: LDS-free, wave-uniform A rows (scalarizable) ----------
// COLS=64: wave = 16 rows x 64 cols, block = 4 waves = 64 rows
// COLS=256: wave = 16 rows x 64-col quadrant, block = 4 waves = full 256 cols
template<int COLS>
__global__ __launch_bounds__(256) void k_gemm(const float* __restrict__ A,
                                              const float* __restrict__ W,
                                              float* __restrict__ Xl){
  int lane = threadIdx.x & 63;
  int wid  = __builtin_amdgcn_readfirstlane(threadIdx.x >> 6);
  int row0, col;
  if constexpr (COLS == 64){ row0 = (blockIdx.x*4 + wid)*16; col = lane; }
  else { row0 = blockIdx.x*16; col = wid*64 + lane; }
  float wreg[64];
#pragma unroll
  for (int k = 0; k < 64; ++k) wreg[k] = W[k*COLS + col];
  float acc[16];
#pragma unroll
  for (int r = 0; r < 16; ++r){
    int row = row0 + r;
    if (COLS == 64 && row >= NN){ acc[r] = 0.f; continue; }
    const float* __restrict__ Ar = A + (size_t)row*64;
    float a = 0.f;
#pragma unroll
    for (int k = 0; k < 64; ++k) a += Ar[k] * wreg[k];
    acc[r] = a;
  }
#pragma unroll
  for (int r = 0; r < 16; ++r){
    int row = row0 + r;
    if (COLS == 64 && row >= NN) continue;
    Xl[(size_t)row*COLS + col] = acc[r];
  }
}

// ---------------- attention coefficients: [N,64] @ [64,8] ----------------
__global__ __launch_bounds__(256) void k_att(const float* __restrict__ A,
                                             const float* __restrict__ Wat,
                                             float* __restrict__ a_src,
                                             float* __restrict__ a_dst){
  int t = blockIdx.x*256 + threadIdx.x;
  if (t >= NN*8) return;
  int n = t >> 3, j = t & 7;
  const float* __restrict__ Ar = A + (size_t)n*64;
  float s = 0.f;
#pragma unroll
  for (int k = 0; k < 64; ++k) s += Ar[k] * Wat[k*8 + j];
  if (j < 4) a_src[n*4 + j] = s;
  else       a_dst[n*4 + (j-4)] = s;
}

// ---------------- layer 1 aggregation: wave per node, lane = h*16+c ------------
__global__ void k_agg1(const float* __restrict__ xl, const float* __restrict__ a_src,
                       const float* __restrict__ a_dst, const float* __restrict__ b1,
                       const int* __restrict__ rowptr, const int* __restrict__ csr,
                       float* __restrict__ h1){
  int lane = threadIdx.x & 63;
  int wid  = threadIdx.x >> 6;
  int n = blockIdx.x*4 + wid;
  int h = lane >> 4;
  float ad = a_dst[n*4 + h];
  int rs = rowptr[n], re = rowptr[n+1];
  float s = 0.f, acc = 0.f;
  int j = rs;
  for (; j + 4 <= re; j += 4){
    int sn0=csr[j], sn1=csr[j+1], sn2=csr[j+2], sn3=csr[j+3];
    float e0=a_src[sn0*4+h], e1=a_src[sn1*4+h], e2=a_src[sn2*4+h], e3=a_src[sn3*4+h];
    float x0=xl[(size_t)sn0*64+lane], x1=xl[(size_t)sn1*64+lane];
    float x2=xl[(size_t)sn2*64+lane], x3=xl[(size_t)sn3*64+lane];
    float p0=__expf(lrelu(e0+ad)), p1=__expf(lrelu(e1+ad));
    float p2=__expf(lrelu(e2+ad)), p3=__expf(lrelu(e3+ad));
    s += p0; acc += p0*x0;
    s += p1; acc += p1*x1;
    s += p2; acc += p2*x2;
    s += p3; acc += p3*x3;
  }
  for (; j < re; ++j){
    int sn = csr[j];
    float p = __expf(lrelu(a_src[sn*4+h] + ad));
    float x = xl[(size_t)sn*64 + lane];
    s += p; acc += p*x;
  }
  h1[(size_t)n*64 + lane] = eluf(acc/(s + 1e-16f) + b1[lane]);
}

// ---------------- layer 2 aggregation: wave per node, ALL 4 heads ---------------
__global__ void k_agg2(const float* __restrict__ xl, const float* __restrict__ a_src,
                       const float* __restrict__ a_dst, const float* __restrict__ b2,
                       const int* __restrict__ rowptr, const int* __restrict__ csr,
                       float* __restrict__ ht){
  int lane = threadIdx.x & 63;
  int wid  = threadIdx.x >> 6;
  int n = blockIdx.x*4 + wid;
  float4 ad = ((const float4*)a_dst)[n];
  int rs = rowptr[n], re = rowptr[n+1];
  const float* xb = xl + lane;
  float s0=0.f,s1=0.f,s2=0.f,s3=0.f;
  float a0=0.f,a1=0.f,a2=0.f,a3=0.f;
  int j = rs;
  for (; j + 2 <= re; j += 2){
    int sna = csr[j], snb = csr[j+1];
    float4 ea = ((const float4*)a_src)[sna];
    float4 eb = ((const float4*)a_src)[snb];
    const float* ra = xb + (size_t)sna*256;
    const float* rb = xb + (size_t)snb*256;
    float xa0=ra[0], xa1=ra[64], xa2=ra[128], xa3=ra[192];
    float xb0=rb[0], xb1=rb[64], xb2=rb[128], xb3=rb[192];
    float pa0=__expf(lrelu(ea.x+ad.x)), pa1=__expf(lrelu(ea.y+ad.y));
    float pa2=__expf(lrelu(ea.z+ad.z)), pa3=__expf(lrelu(ea.w+ad.w));
    float pb0=__expf(lrelu(eb.x+ad.x)), pb1=__expf(lrelu(eb.y+ad.y));
    float pb2=__expf(lrelu(eb.z+ad.z)), pb3=__expf(lrelu(eb.w+ad.w));
    s0 += pa0 + pb0; a0 += pa0*xa0 + pb0*xb0;
    s1 += pa1 + pb1; a1 += pa1*xa1 + pb1*xb1;
    s2 += pa2 + pb2; a2 += pa2*xa2 + pb2*xb2;
    s3 += pa3 + pb3; a3 += pa3*xa3 + pb3*xb3;
  }
  for (; j < re; ++j){
    int sn = csr[j];
    float4 ev = ((const float4*)a_src)[sn];
    const float* r = xb + (size_t)sn*256;
    float p0=__expf(lrelu(ev.x+ad.x)), p1=__expf(lrelu(ev.y+ad.y));
    float p2=__expf(lrelu(ev.z+ad.z)), p3=__expf(lrelu(ev.w+ad.w));
    s0 += p0; a0 += p0*r[0];
    s1 += p1; a1 += p1*r[64];
    s2 += p2; a2 += p2*r[128];
    s3 += p3; a3 += p3*r[192];
  }
  float o = 0.25f*(a0/(s0+1e-16f) + a1/(s1+1e-16f) + a2/(s2+1e-16f) + a3/(s3+1e-16f));
  ht[(size_t)n*64 + lane] = eluf(o + b2[lane]);
}

// ---------------- temporal stack: one wave per node, ZERO LDS in convs ----------
// Storage: lane = channel i holds X[i][t] in regs; compute: lane = out-channel o.
// Broadcast via v_readlane (uniform loop index). conv1->conv2 transition is identity.
__global__ __launch_bounds__(256) void k_temporal(
    const float* __restrict__ htb,
    const float4* __restrict__ w1p, const float* __restrict__ cb1,
    const float* __restrict__ g1,   const float* __restrict__ be1,
    const float4* __restrict__ w2p, const float* __restrict__ cb2,
    const float* __restrict__ g2,   const float* __restrict__ be2,
    const float* __restrict__ lw1,  const float* __restrict__ lb1,
    const float* __restrict__ lw2,  const float* __restrict__ lb2,
    float* __restrict__ out){
  int lane = threadIdx.x & 63;
  int n = blockIdx.x*4 + (threadIdx.x >> 6);   // grid 12500 x 4 waves = 50000

  // stage: lane=channel, 6 coalesced b32 loads
  float x1 = htb[((size_t)0*NN + n)*64 + lane];
  float x2 = htb[((size_t)1*NN + n)*64 + lane];
  float x3 = htb[((size_t)2*NN + n)*64 + lane];
  float x4 = htb[((size_t)3*NN + n)*64 + lane];
  float x5 = htb[((size_t)4*NN + n)*64 + lane];
  float x6 = htb[((size_t)5*NN + n)*64 + lane];

  float acc0, acc1, acc2, acc3, acc4, acc5;

  // ---- conv1 ----
  {
    float c = cb1[lane];
    acc0=c; acc1=c; acc2=c; acc3=c; acc4=c; acc5=c;
    for (int i = 0; i < 64; ++i){
      float4 w = w1p[(i<<6) + lane];
      float s1=RL(x1,i), s2=RL(x2,i), s3=RL(x3,i);
      float s4=RL(x4,i), s5=RL(x5,i), s6=RL(x6,i);
      acc0 += w.y*s1 + w.z*s2;
      acc1 += w.x*s1 + w.y*s2 + w.z*s3;
      acc2 += w.x*s2 + w.y*s3 + w.z*s4;
      acc3 += w.x*s3 + w.y*s4 + w.z*s5;
      acc4 += w.x*s4 + w.y*s5 + w.z*s6;
      acc5 += w.x*s5 + w.y*s6;
    }
    float bns = g1[lane]*rsqrtf(1.f + 1e-5f), be = be1[lane];
    x1 = fmaxf(acc0*bns + be, 0.f);
    x2 = fmaxf(acc1*bns + be, 0.f);
    x3 = fmaxf(acc2*bns + be, 0.f);
    x4 = fmaxf(acc3*bns + be, 0.f);
    x5 = fmaxf(acc4*bns + be, 0.f);
    x6 = fmaxf(acc5*bns + be, 0.f);
  }
  // ---- conv2 ----
  {
    float c = cb2[lane];
    acc0=c; acc1=c; acc2=c; acc3=c; acc4=c; acc5=c;
    for (int i = 0; i < 64; ++i){
      float4 w = w2p[(i<<6) + lane];
      float s1=RL(x1,i), s2=RL(x2,i), s3=RL(x3,i);
      float s4=RL(x4,i), s5=RL(x5,i), s6=RL(x6,i);
      acc0 += w.y*s1 + w.z*s2;
      acc1 += w.x*s1 + w.y*s2 + w.z*s3;
      acc2 += w.x*s2 + w.y*s3 + w.z*s4;
      acc3 += w.x*s3 + w.y*s4 + w.z*s5;
      acc4 += w.x*s4 + w.y*s5 + w.z*s6;
      acc5 += w.x*s5 + w.y*s6;
    }
    float bns = g2[lane]*rsqrtf(1.f + 1e-5f), be = be2[lane];
    float pooled = fmaxf(acc0*bns + be, 0.f) + fmaxf(acc1*bns + be, 0.f)
                 + fmaxf(acc2*bns + be, 0.f) + fmaxf(acc3*bns + be, 0.f)
                 + fmaxf(acc4*bns + be, 0.f) + fmaxf(acc5*bns + be, 0.f);
    x1 = pooled*(1.f/6.f);          // pooled, per lane=channel
  }
  // ---- MLP: h = relu(pooled @ lw1 + lb1); out = h @ lw2 + lb2 ----
  {
    int j = lane & 31;
    float hacc = 0.f;
    for (int k = 0; k < 64; ++k){
      float pk = RL(x1, k);
      hacc += pk * lw1[k*32 + j];
    }
    float part = fmaxf(hacc + lb1[j], 0.f) * lw2[j];
    if (lane >= 32) part = 0.f;
    part += __shfl_xor(part, 32);
    part += __shfl_xor(part, 16);
    part += __shfl_xor(part, 8);
    part += __shfl_xor(part, 4);
    part += __shfl_xor(part, 2);
    part += __shfl_xor(part, 1);
    if (lane == 0) out[n] = part + lb2[0];
  }
}

// ---------------- launch ----------------
extern "C" void kernel_launch(void* const* d_in, const int* in_sizes, int n_in,
                              void* d_out, int out_size, void* d_ws, size_t ws_size,
                              hipStream_t stream) {
  const float* x_seq = (const float*)d_in[0];
  const int*   ei    = (const int*)  d_in[1];
  const float* W1  = (const float*)d_in[2];
  const float* as1 = (const float*)d_in[3];
  const float* ad1 = (const float*)d_in[4];
  const float* b1  = (const float*)d_in[5];
  const float* W2  = (const float*)d_in[6];
  const float* as2 = (const float*)d_in[7];
  const float* ad2 = (const float*)d_in[8];
  const float* b2  = (const float*)d_in[9];
  const float* cw1 = (const float*)d_in[10];
  const float* cb1 = (const float*)d_in[11];
  const float* g1  = (const float*)d_in[12];
  const float* be1 = (const float*)d_in[13];
  const float* cw2 = (const float*)d_in[14];
  const float* cb2 = (const float*)d_in[15];
  const float* g2  = (const float*)d_in[16];
  const float* be2 = (const float*)d_in[17];
  const float* lw1 = (const float*)d_in[18];
  const float* lb1 = (const float*)d_in[19];
  const float* lw2 = (const float*)d_in[20];
  const float* lb2 = (const float*)d_in[21];
  float* out = (float*)d_out;

  char* wp = (char*)d_ws;
  auto alloc = [&](size_t bytes) -> char* {
    char* p = wp; wp += (bytes + 255) & ~(size_t)255; return p;
  };
  int*   counts = (int*)  alloc(NN*sizeof(int));
  int*   excl   = (int*)  alloc(NN*sizeof(int));
  int*   bsum   = (int*)  alloc(64*sizeof(int));
  int*   rowptr = (int*)  alloc((NN+1)*sizeof(int));
  int*   cursor = (int*)  alloc(NN*sizeof(int));
  int*   csr    = (int*)  alloc((size_t)(EE+NN)*sizeof(int));
  float* a_src  = (float*)alloc((size_t)NN*4*sizeof(float));
  float* a_dst  = (float*)alloc((size_t)NN*4*sizeof(float));
  float* xl     = (float*)alloc((size_t)NN*256*sizeof(float));
  float* h1     = (float*)alloc((size_t)NN*64*sizeof(float));
  float* htb    = (float*)alloc((size_t)TT*NN*64*sizeof(float));
  float* Wat1   = (float*)alloc(64*8*sizeof(float));
  float* Wat2   = (float*)alloc(64*8*sizeof(float));
  float4* w1p   = (float4*)alloc(64*64*sizeof(float4));
  float4* w2p   = (float4*)alloc(64*64*sizeof(float4));

  const int NBSCAN = (NN + 1023)/1024;   // 49
  k_init_counts<<<(NN+255)/256, 256, 0, stream>>>(counts);
  k_hist<<<(EE+255)/256, 256, 0, stream>>>(ei + EE, counts);
  k_scanA<<<NBSCAN, 1024, 0, stream>>>(counts, excl, bsum);
  k_scanB<<<1, 64, 0, stream>>>(bsum, NBSCAN);
  k_scanC<<<NBSCAN, 1024, 0, stream>>>(excl, bsum, rowptr, cursor);
  k_scatter<<<(EE+NN+255)/256, 256, 0, stream>>>(ei, cursor, csr);
  k_prep<<<1, 256, 0, stream>>>(W1, as1, ad1, W2, as2, ad2, cw1, cw2,
                                Wat1, Wat2, w1p, w2p);

  for (int t = 0; t < TT; ++t){
    const float* xt = x_seq + (size_t)t*NN*64;
    k_gemm<64><<<(NN+63)/64, 256, 0, stream>>>(xt, W1, xl);
    k_att<<<(NN*8+255)/256, 256, 0, stream>>>(xt, Wat1, a_src, a_dst);
    k_agg1<<<NN/4, 256, 0, stream>>>(xl, a_src, a_dst, b1, rowptr, csr, h1);
    k_gemm<256><<<NN/16, 256, 0, stream>>>(h1, W2, xl);
    k_att<<<(NN*8+255)/256, 256, 0, stream>>>(h1, Wat2, a_src, a_dst);
    k_agg2<<<NN/4, 256, 0, stream>>>(xl, a_src, a_dst, b2, rowptr, csr,
                                     htb + (size_t)t*NN*64);
  }
  k_temporal<<<NN/4, 256, 0, stream>>>(htb, w1p, cb1, g1, be1, w2p, cb2, g2, be2,
                                       lw1, lb1, lw2, lb2, out);
}

// Round 5
// 1623.307 us; speedup vs baseline: 1.2291x; 1.2291x over previous
//
#include <hip/hip_runtime.h>
#include <math.h>

#define NN 50000
#define EE 800000
#define TT 6

__device__ __forceinline__ float lrelu(float x){ return x > 0.f ? x : 0.2f*x; }
__device__ __forceinline__ float eluf(float x){ return x > 0.f ? x : expm1f(x); }
#define RL(v,i) __uint_as_float(__builtin_amdgcn_readlane(__float_as_uint(v), (i)))

// ---------------- CSR build ----------------
__global__ void k_init_counts(int* __restrict__ c){
  int i = blockIdx.x*256 + threadIdx.x;
  if (i < NN) c[i] = 1;
}

__global__ void k_hist(const int* __restrict__ dst, int* __restrict__ c){
  int i = blockIdx.x*256 + threadIdx.x;
  if (i < EE) atomicAdd(&c[dst[i]], 1);
}

__global__ void k_scanA(const int* __restrict__ cnt, int* __restrict__ excl,
                        int* __restrict__ bsum){
  __shared__ int sh[1024];
  int tid = threadIdx.x;
  int i = blockIdx.x*1024 + tid;
  int v = (i < NN) ? cnt[i] : 0;
  int x = v;
  sh[tid] = x; __syncthreads();
  for (int off = 1; off < 1024; off <<= 1){
    int y = (tid >= off) ? sh[tid - off] : 0;
    __syncthreads();
    x += y; sh[tid] = x; __syncthreads();
  }
  if (i < NN) excl[i] = x - v;
  if (tid == 1023) bsum[blockIdx.x] = x;
}

__global__ void k_scanB(int* __restrict__ bsum, int nb){
  if (threadIdx.x == 0){
    int run = 0;
    for (int b = 0; b < nb; ++b){ int t = bsum[b]; bsum[b] = run; run += t; }
  }
}

__global__ void k_scanC(const int* __restrict__ excl, const int* __restrict__ bsum,
                        int* __restrict__ rowptr, int* __restrict__ cursor){
  int i = blockIdx.x*1024 + threadIdx.x;
  if (i < NN){
    int v = excl[i] + bsum[blockIdx.x];
    rowptr[i] = v; cursor[i] = v;
  }
  if (i == 0) rowptr[NN] = EE + NN;
}

__global__ void k_scatter(const int* __restrict__ ei, int* __restrict__ cursor,
                          int* __restrict__ csr){
  int i = blockIdx.x*256 + threadIdx.x;
  if (i < EE){
    int d = ei[EE + i];
    int p = atomicAdd(&cursor[d], 1);
    csr[p] = ei[i];
  } else if (i < EE + NN){
    int v = i - EE;
    int p = atomicAdd(&cursor[v], 1);
    csr[p] = v;
  }
}

// ---------------- weight preprocessing ----------------
// Was1/Wad1: [k][h] folded attention for layer1 (a = x @ (W1·att))
// Wat2: [k][8] merged src/dst for layer2.  Wb: [(h*64+kk)][c] = W2[kk][h*64+c]
__global__ void k_prep(const float* __restrict__ W1, const float* __restrict__ as1,
                       const float* __restrict__ ad1,
                       const float* __restrict__ W2, const float* __restrict__ as2,
                       const float* __restrict__ ad2,
                       const float* __restrict__ cw1, const float* __restrict__ cw2,
                       float* __restrict__ Was1, float* __restrict__ Wad1,
                       float* __restrict__ Wat2, float* __restrict__ Wb,
                       float4* __restrict__ w1p, float4* __restrict__ w2p){
  int tid = threadIdx.x;          // 256
  int k = tid >> 2, h = tid & 3;
  float s1 = 0.f, d1 = 0.f, s2 = 0.f, d2 = 0.f;
  for (int c = 0; c < 16; ++c){
    float w = W1[k*64 + h*16 + c];
    s1 += w * as1[h*16 + c];
    d1 += w * ad1[h*16 + c];
  }
  for (int c = 0; c < 64; ++c){
    float w = W2[k*256 + h*64 + c];
    s2 += w * as2[h*64 + c];
    d2 += w * ad2[h*64 + c];
  }
  Was1[k*4+h] = s1; Wad1[k*4+h] = d1;
  Wat2[k*8 + h] = s2; Wat2[k*8 + 4 + h] = d2;
  for (int idx = tid; idx < 256*64; idx += 256){
    int kf = idx >> 6, c = idx & 63;
    int hh = kf >> 6, kk = kf & 63;
    Wb[idx] = W2[kk*256 + hh*64 + c];
  }
  for (int idx = tid; idx < 64*64; idx += 256){
    int o = idx & 63, i = idx >> 6;
    w1p[idx] = make_float4(cw1[o*192+i*3], cw1[o*192+i*3+1], cw1[o*192+i*3+2], 0.f);
    w2p[idx] = make_float4(cw2[o*192+i*3], cw2[o*192+i*3+1], cw2[o*192+i*3+2], 0.f);
  }
}

// ---------------- layer-1 GEMM (N x 64 @ 64 x 64) + fused attention epilogue ----
__global__ __launch_bounds__(256) void k_gemm_att1(const float* __restrict__ A,
                            const float* __restrict__ W,
                            const float* __restrict__ Was, const float* __restrict__ Wad,
                            float* __restrict__ Xl, float* __restrict__ a_src,
                            float* __restrict__ a_dst){
  __shared__ float At[64][16];
  int tid = threadIdx.x;
  int r0 = blockIdx.x * 16;
  {
    const float4* A4 = (const float4*)(A + (size_t)r0*64);
    float4 v = A4[tid];
    int r = tid >> 4, k4 = (tid & 15) << 2;
    At[k4+0][r] = v.x; At[k4+1][r] = v.y;
    At[k4+2][r] = v.z; At[k4+3][r] = v.w;
  }
  __syncthreads();
  int col = tid & 63;
  int rbase = (tid >> 6) << 2;
  float acc0=0.f, acc1=0.f, acc2=0.f, acc3=0.f;
  for (int k = 0; k < 64; ++k){
    float w = W[k*64 + col];
    float4 a4 = *(const float4*)&At[k][rbase];
    acc0 += a4.x*w; acc1 += a4.y*w; acc2 += a4.z*w; acc3 += a4.w*w;
  }
  Xl[(size_t)(r0+rbase+0)*64 + col] = acc0;
  Xl[(size_t)(r0+rbase+1)*64 + col] = acc1;
  Xl[(size_t)(r0+rbase+2)*64 + col] = acc2;
  Xl[(size_t)(r0+rbase+3)*64 + col] = acc3;
  if (tid < 128){
    int r = tid >> 3, jx = tid & 7;
    int h = jx & 3;
    const float* Wv = (jx < 4) ? Was : Wad;
    float a = 0.f;
    for (int k = 0; k < 64; ++k) a += At[k][r] * Wv[k*4 + h];
    if (jx < 4) a_src[(r0 + r)*4 + h] = a;
    else        a_dst[(r0 + r)*4 + h] = a;
  }
}

// ---------------- attention coefficients from h1: [N,64] @ [64,8] ----------------
__global__ __launch_bounds__(256) void k_att(const float* __restrict__ A,
                                             const float* __restrict__ Wat,
                                             float* __restrict__ a_src,
                                             float* __restrict__ a_dst){
  int lane = threadIdx.x & 63;
  int wid  = threadIdx.x >> 6;
  int q = lane >> 3, j = lane & 7;
  int n = blockIdx.x*32 + wid*8 + q;
  if (n >= NN) return;
  const float* __restrict__ Ar = A + (size_t)n*64;
  float s = 0.f;
#pragma unroll 8
  for (int k = 0; k < 64; ++k) s += Ar[k] * Wat[k*8 + j];
  if (j < 4) a_src[n*4 + j] = s;
  else       a_dst[n*4 + (j-4)] = s;
}

// ---------------- layer 1 aggregation: wave per node, lane = h*16+c ------------
__global__ void k_agg1(const float* __restrict__ xl, const float* __restrict__ a_src,
                       const float* __restrict__ a_dst, const float* __restrict__ b1,
                       const int* __restrict__ rowptr, const int* __restrict__ csr,
                       float* __restrict__ h1){
  int lane = threadIdx.x & 63;
  int wid  = threadIdx.x >> 6;
  int n = blockIdx.x*4 + wid;
  int h = lane >> 4;
  float ad = a_dst[n*4 + h];
  int rs = rowptr[n], re = rowptr[n+1];
  float s = 0.f, acc = 0.f;
  int j = rs;
  for (; j + 4 <= re; j += 4){
    int sn0=csr[j], sn1=csr[j+1], sn2=csr[j+2], sn3=csr[j+3];
    float e0=a_src[sn0*4+h], e1=a_src[sn1*4+h], e2=a_src[sn2*4+h], e3=a_src[sn3*4+h];
    float x0=xl[(size_t)sn0*64+lane], x1=xl[(size_t)sn1*64+lane];
    float x2=xl[(size_t)sn2*64+lane], x3=xl[(size_t)sn3*64+lane];
    float p0=__expf(lrelu(e0+ad)), p1=__expf(lrelu(e1+ad));
    float p2=__expf(lrelu(e2+ad)), p3=__expf(lrelu(e3+ad));
    s += p0; acc += p0*x0;
    s += p1; acc += p1*x1;
    s += p2; acc += p2*x2;
    s += p3; acc += p3*x3;
  }
  for (; j < re; ++j){
    int sn = csr[j];
    float p = __expf(lrelu(a_src[sn*4+h] + ad));
    float x = xl[(size_t)sn*64 + lane];
    s += p; acc += p*x;
  }
  h1[(size_t)n*64 + lane] = eluf(acc/(s + 1e-16f) + b1[lane]);
}

// ---------------- layer 2 aggregation over h1 (commuted past W2) ----------------
// G[n][h][k] = (1/s_h) * sum_e alpha^h_e h1[src_e][k]; lane = k, 4 head-accums
__global__ void k_agg2(const float* __restrict__ h1, const float* __restrict__ a_src,
                       const float* __restrict__ a_dst,
                       const int* __restrict__ rowptr, const int* __restrict__ csr,
                       float* __restrict__ agg){
  int lane = threadIdx.x & 63;
  int wid  = threadIdx.x >> 6;
  int n = blockIdx.x*4 + wid;
  float4 ad = ((const float4*)a_dst)[n];
  int rs = rowptr[n], re = rowptr[n+1];
  float s0=0.f,s1=0.f,s2=0.f,s3=0.f;
  float g0=0.f,g1=0.f,g2=0.f,g3=0.f;
  int j = rs;
  for (; j + 4 <= re; j += 4){
    int sa=csr[j], sb=csr[j+1], sc=csr[j+2], sd=csr[j+3];
    float4 ea = ((const float4*)a_src)[sa];
    float4 eb = ((const float4*)a_src)[sb];
    float4 ec = ((const float4*)a_src)[sc];
    float4 ed = ((const float4*)a_src)[sd];
    float xa = h1[(size_t)sa*64 + lane];
    float xb = h1[(size_t)sb*64 + lane];
    float xc = h1[(size_t)sc*64 + lane];
    float xd = h1[(size_t)sd*64 + lane];
    float pa0=__expf(lrelu(ea.x+ad.x)), pa1=__expf(lrelu(ea.y+ad.y));
    float pa2=__expf(lrelu(ea.z+ad.z)), pa3=__expf(lrelu(ea.w+ad.w));
    float pb0=__expf(lrelu(eb.x+ad.x)), pb1=__expf(lrelu(eb.y+ad.y));
    float pb2=__expf(lrelu(eb.z+ad.z)), pb3=__expf(lrelu(eb.w+ad.w));
    float pc0=__expf(lrelu(ec.x+ad.x)), pc1=__expf(lrelu(ec.y+ad.y));
    float pc2=__expf(lrelu(ec.z+ad.z)), pc3=__expf(lrelu(ec.w+ad.w));
    float pd0=__expf(lrelu(ed.x+ad.x)), pd1=__expf(lrelu(ed.y+ad.y));
    float pd2=__expf(lrelu(ed.z+ad.z)), pd3=__expf(lrelu(ed.w+ad.w));
    s0 += pa0+pb0+pc0+pd0; g0 += pa0*xa + pb0*xb + pc0*xc + pd0*xd;
    s1 += pa1+pb1+pc1+pd1; g1 += pa1*xa + pb1*xb + pc1*xc + pd1*xd;
    s2 += pa2+pb2+pc2+pd2; g2 += pa2*xa + pb2*xb + pc2*xc + pd2*xd;
    s3 += pa3+pb3+pc3+pd3; g3 += pa3*xa + pb3*xb + pc3*xc + pd3*xd;
  }
  for (; j < re; ++j){
    int sn = csr[j];
    float4 ev = ((const float4*)a_src)[sn];
    float x = h1[(size_t)sn*64 + lane];
    float p0=__expf(lrelu(ev.x+ad.x)), p1=__expf(lrelu(ev.y+ad.y));
    float p2=__expf(lrelu(ev.z+ad.z)), p3=__expf(lrelu(ev.w+ad.w));
    s0 += p0; g0 += p0*x;
    s1 += p1; g1 += p1*x;
    s2 += p2; g2 += p2*x;
    s3 += p3; g3 += p3*x;
  }
  size_t base = (size_t)n*256 + lane;
  agg[base      ] = g0/(s0 + 1e-16f);
  agg[base +  64] = g1/(s1 + 1e-16f);
  agg[base + 128] = g2/(s2 + 1e-16f);
  agg[base + 192] = g3/(s3 + 1e-16f);
}

// ---------------- layer-2 output GEMM: [N,256] @ Wb[256,64], +b2, elu ------------
// wave = 4 rows x 64 cols; A rows read via wave-uniform loads (scalarizable)
__global__ __launch_bounds__(256) void k_out2(const float* __restrict__ agg,
                                              const float* __restrict__ Wb,
                                              const float* __restrict__ b2,
                                              float* __restrict__ ht){
  int lane = threadIdx.x & 63;
  int wid  = __builtin_amdgcn_readfirstlane(threadIdx.x >> 6);
  int r0 = blockIdx.x*16 + wid*4;
  const float* __restrict__ a0 = agg + (size_t)r0*256;
  float acc0=0.f, acc1=0.f, acc2=0.f, acc3=0.f;
#pragma unroll 4
  for (int k = 0; k < 256; ++k){
    float w = Wb[k*64 + lane];
    acc0 += a0[k      ]*w;
    acc1 += a0[k + 256]*w;
    acc2 += a0[k + 512]*w;
    acc3 += a0[k + 768]*w;
  }
  float bb = b2[lane];
  ht[(size_t)(r0+0)*64 + lane] = eluf(0.25f*acc0 + bb);
  ht[(size_t)(r0+1)*64 + lane] = eluf(0.25f*acc1 + bb);
  ht[(size_t)(r0+2)*64 + lane] = eluf(0.25f*acc2 + bb);
  ht[(size_t)(r0+3)*64 + lane] = eluf(0.25f*acc3 + bb);
}

// ---------------- transpose htb[t][n][ch] -> Xp[n][ch][6] ----------------
__global__ __launch_bounds__(256) void k_xpose(const float* __restrict__ htb,
                                               float* __restrict__ Xp){
  int ch = threadIdx.x & 63;
  int q  = threadIdx.x >> 6;
  int n = blockIdx.x*4 + q;
  float r0 = htb[((size_t)0*NN + n)*64 + ch];
  float r1 = htb[((size_t)1*NN + n)*64 + ch];
  float r2 = htb[((size_t)2*NN + n)*64 + ch];
  float r3 = htb[((size_t)3*NN + n)*64 + ch];
  float r4 = htb[((size_t)4*NN + n)*64 + ch];
  float r5 = htb[((size_t)5*NN + n)*64 + ch];
  float* dst = Xp + (size_t)n*384 + ch*6;
  *(float2*)(dst+0) = make_float2(r0,r1);
  *(float2*)(dst+2) = make_float2(r2,r3);
  *(float2*)(dst+4) = make_float2(r4,r5);
}

// ---------------- temporal stack: uniform-global broadcast, zero LDS ------------
// wave = 4 nodes; lane = out-channel; X broadcast via wave-uniform loads of Xp rows;
// conv1 output written back in-place to Xp (wave-private rows), re-read by conv2.
__global__ __launch_bounds__(256) void k_temporal(
    float* __restrict__ Xp,
    const float4* __restrict__ w1p, const float* __restrict__ cb1,
    const float* __restrict__ g1,   const float* __restrict__ be1,
    const float4* __restrict__ w2p, const float* __restrict__ cb2,
    const float* __restrict__ g2,   const float* __restrict__ be2,
    const float* __restrict__ lw1,  const float* __restrict__ lb1,
    const float* __restrict__ lw2,  const float* __restrict__ lb2,
    float* __restrict__ out){
  int lane = threadIdx.x & 63;
  int wid  = __builtin_amdgcn_readfirstlane(threadIdx.x >> 6);
  int n0 = (blockIdx.x*4 + wid)*4;
  float* xb = Xp + (size_t)n0*384;

  float acc[4][6];
  // ---- conv1 ----
  {
    float c = cb1[lane];
#pragma unroll
    for (int q=0;q<4;++q){
#pragma unroll
      for (int t=0;t<6;++t) acc[q][t]=c;
    }
    for (int i = 0; i < 64; ++i){
      float4 w = w1p[(i<<6) + lane];
      const float* xr = xb + i*6;
#pragma unroll
      for (int q = 0; q < 4; ++q){
        float2 A2 = *(const float2*)(xr + q*384);
        float2 B2 = *(const float2*)(xr + q*384 + 2);
        float2 C2 = *(const float2*)(xr + q*384 + 4);
        acc[q][0] += w.y*A2.x + w.z*A2.y;
        acc[q][1] += w.x*A2.x + w.y*A2.y + w.z*B2.x;
        acc[q][2] += w.x*A2.y + w.y*B2.x + w.z*B2.y;
        acc[q][3] += w.x*B2.x + w.y*B2.y + w.z*C2.x;
        acc[q][4] += w.x*B2.y + w.y*C2.x + w.z*C2.y;
        acc[q][5] += w.x*C2.x + w.y*C2.y;
      }
    }
    float bns = g1[lane]*rsqrtf(1.f + 1e-5f), be = be1[lane];
#pragma unroll
    for (int q=0;q<4;++q){
      float* dp = xb + q*384 + lane*6;
      float r0 = fmaxf(acc[q][0]*bns + be, 0.f);
      float r1 = fmaxf(acc[q][1]*bns + be, 0.f);
      float r2 = fmaxf(acc[q][2]*bns + be, 0.f);
      float r3 = fmaxf(acc[q][3]*bns + be, 0.f);
      float r4 = fmaxf(acc[q][4]*bns + be, 0.f);
      float r5 = fmaxf(acc[q][5]*bns + be, 0.f);
      *(float2*)(dp+0) = make_float2(r0,r1);
      *(float2*)(dp+2) = make_float2(r2,r3);
      *(float2*)(dp+4) = make_float2(r4,r5);
    }
  }
  // ---- conv2 + pool ----
  float p0, p1, p2, p3;
  {
    float c = cb2[lane];
#pragma unroll
    for (int q=0;q<4;++q){
#pragma unroll
      for (int t=0;t<6;++t) acc[q][t]=c;
    }
    for (int i = 0; i < 64; ++i){
      float4 w = w2p[(i<<6) + lane];
      const float* xr = xb + i*6;
#pragma unroll
      for (int q = 0; q < 4; ++q){
        float2 A2 = *(const float2*)(xr + q*384);
        float2 B2 = *(const float2*)(xr + q*384 + 2);
        float2 C2 = *(const float2*)(xr + q*384 + 4);
        acc[q][0] += w.y*A2.x + w.z*A2.y;
        acc[q][1] += w.x*A2.x + w.y*A2.y + w.z*B2.x;
        acc[q][2] += w.x*A2.y + w.y*B2.x + w.z*B2.y;
        acc[q][3] += w.x*B2.x + w.y*B2.y + w.z*C2.x;
        acc[q][4] += w.x*B2.y + w.y*C2.x + w.z*C2.y;
        acc[q][5] += w.x*C2.x + w.y*C2.y;
      }
    }
    float bns = g2[lane]*rsqrtf(1.f + 1e-5f), be = be2[lane];
    float pl[4];
#pragma unroll
    for (int q=0;q<4;++q){
      float s = 0.f;
#pragma unroll
      for (int t=0;t<6;++t) s += fmaxf(acc[q][t]*bns + be, 0.f);
      pl[q] = s*(1.f/6.f);
    }
    p0 = pl[0]; p1 = pl[1]; p2 = pl[2]; p3 = pl[3];
  }
  // ---- MLP (cold; readlane broadcast is fine here) ----
  {
    int j = lane & 31;
    float lb = lb1[j], w2v = lw2[j];
    float h0=0.f, h1v=0.f, h2=0.f, h3=0.f;
    for (int k = 0; k < 64; ++k){
      float lw = lw1[k*32 + j];
      h0  += RL(p0, k)*lw;
      h1v += RL(p1, k)*lw;
      h2  += RL(p2, k)*lw;
      h3  += RL(p3, k)*lw;
    }
    float o0 = fmaxf(h0 +lb, 0.f)*w2v;
    float o1 = fmaxf(h1v+lb, 0.f)*w2v;
    float o2 = fmaxf(h2 +lb, 0.f)*w2v;
    float o3 = fmaxf(h3 +lb, 0.f)*w2v;
#pragma unroll
    for (int off = 16; off >= 1; off >>= 1){
      o0 += __shfl_xor(o0, off);
      o1 += __shfl_xor(o1, off);
      o2 += __shfl_xor(o2, off);
      o3 += __shfl_xor(o3, off);
    }
    if (lane == 0){
      float b = lb2[0];
      out[n0+0] = o0 + b;
      out[n0+1] = o1 + b;
      out[n0+2] = o2 + b;
      out[n0+3] = o3 + b;
    }
  }
}

// ---------------- launch ----------------
extern "C" void kernel_launch(void* const* d_in, const int* in_sizes, int n_in,
                              void* d_out, int out_size, void* d_ws, size_t ws_size,
                              hipStream_t stream) {
  const float* x_seq = (const float*)d_in[0];
  const int*   ei    = (const int*)  d_in[1];
  const float* W1  = (const float*)d_in[2];
  const float* as1 = (const float*)d_in[3];
  const float* ad1 = (const float*)d_in[4];
  const float* b1  = (const float*)d_in[5];
  const float* W2  = (const float*)d_in[6];
  const float* as2 = (const float*)d_in[7];
  const float* ad2 = (const float*)d_in[8];
  const float* b2  = (const float*)d_in[9];
  const float* cw1 = (const float*)d_in[10];
  const float* cb1 = (const float*)d_in[11];
  const float* g1  = (const float*)d_in[12];
  const float* be1 = (const float*)d_in[13];
  const float* cw2 = (const float*)d_in[14];
  const float* cb2 = (const float*)d_in[15];
  const float* g2  = (const float*)d_in[16];
  const float* be2 = (const float*)d_in[17];
  const float* lw1 = (const float*)d_in[18];
  const float* lb1 = (const float*)d_in[19];
  const float* lw2 = (const float*)d_in[20];
  const float* lb2 = (const float*)d_in[21];
  float* out = (float*)d_out;

  char* wp = (char*)d_ws;
  auto alloc = [&](size_t bytes) -> char* {
    char* p = wp; wp += (bytes + 255) & ~(size_t)255; return p;
  };
  // persistent across whole call
  float* htb  = (float*)alloc((size_t)TT*NN*64*sizeof(float));   // 76.8 MB
  float* Was1 = (float*)alloc(256*sizeof(float));
  float* Wad1 = (float*)alloc(256*sizeof(float));
  float* Wat2 = (float*)alloc(64*8*sizeof(float));
  float* Wb   = (float*)alloc(256*64*sizeof(float));
  float4* w1p = (float4*)alloc(64*64*sizeof(float4));
  float4* w2p = (float4*)alloc(64*64*sizeof(float4));
  // scratch region (dead after the t-loop) — Xp aliases it
  char* scratch0 = wp;
  int*   counts = (int*)  alloc(NN*sizeof(int));
  int*   excl   = (int*)  alloc(NN*sizeof(int));
  int*   bsum   = (int*)  alloc(64*sizeof(int));
  int*   rowptr = (int*)  alloc((NN+1)*sizeof(int));
  int*   cursor = (int*)  alloc(NN*sizeof(int));
  int*   csr    = (int*)  alloc((size_t)(EE+NN)*sizeof(int));
  float* a_src  = (float*)alloc((size_t)NN*4*sizeof(float));
  float* a_dst  = (float*)alloc((size_t)NN*4*sizeof(float));
  float* h1     = (float*)alloc((size_t)NN*64*sizeof(float));
  float* agg    = (float*)alloc((size_t)NN*256*sizeof(float));   // also used as xl1
  float* xl1    = agg;                       // layer-1 features (dead before agg write)
  float* Xp     = (float*)scratch0;          // [NN][64][6] = 76.8 MB, aliases scratch

  const int NBSCAN = (NN + 1023)/1024;   // 49
  k_init_counts<<<(NN+255)/256, 256, 0, stream>>>(counts);
  k_hist<<<(EE+255)/256, 256, 0, stream>>>(ei + EE, counts);
  k_scanA<<<NBSCAN, 1024, 0, stream>>>(counts, excl, bsum);
  k_scanB<<<1, 64, 0, stream>>>(bsum, NBSCAN);
  k_scanC<<<NBSCAN, 1024, 0, stream>>>(excl, bsum, rowptr, cursor);
  k_scatter<<<(EE+NN+255)/256, 256, 0, stream>>>(ei, cursor, csr);
  k_prep<<<1, 256, 0, stream>>>(W1, as1, ad1, W2, as2, ad2, cw1, cw2,
                                Was1, Wad1, Wat2, Wb, w1p, w2p);

  for (int t = 0; t < TT; ++t){
    const float* xt = x_seq + (size_t)t*NN*64;
    k_gemm_att1<<<NN/16, 256, 0, stream>>>(xt, W1, Was1, Wad1, xl1, a_src, a_dst);
    k_agg1<<<NN/4, 256, 0, stream>>>(xl1, a_src, a_dst, b1, rowptr, csr, h1);
    k_att<<<(NN+31)/32, 256, 0, stream>>>(h1, Wat2, a_src, a_dst);
    k_agg2<<<NN/4, 256, 0, stream>>>(h1, a_src, a_dst, rowptr, csr, agg);
    k_out2<<<NN/16, 256, 0, stream>>>(agg, Wb, b2, htb + (size_t)t*NN*64);
  }
  k_xpose<<<NN/4, 256, 0, stream>>>(htb, Xp);
  k_temporal<<<NN/16, 256, 0, stream>>>(Xp, w1p, cb1, g1, be1, w2p, cb2, g2, be2,
                                        lw1, lb1, lw2, lb2, out);
}

// Round 6
// 1431.525 us; speedup vs baseline: 1.3937x; 1.1340x over previous
//
#include <hip/hip_runtime.h>
#include <math.h>

#define NN 50000
#define EE 800000
#define TT 6

__device__ __forceinline__ float lrelu(float x){ return x > 0.f ? x : 0.2f*x; }
__device__ __forceinline__ float eluf(float x){ return x > 0.f ? x : expm1f(x); }

// ---------------- CSR build ----------------
__global__ void k_init_counts(int* __restrict__ c){
  int i = blockIdx.x*256 + threadIdx.x;
  if (i < NN) c[i] = 1;
}

__global__ void k_hist(const int* __restrict__ dst, int* __restrict__ c){
  int i = blockIdx.x*256 + threadIdx.x;
  if (i < EE) atomicAdd(&c[dst[i]], 1);
}

__global__ void k_scanA(const int* __restrict__ cnt, int* __restrict__ excl,
                        int* __restrict__ bsum){
  __shared__ int sh[1024];
  int tid = threadIdx.x;
  int i = blockIdx.x*1024 + tid;
  int v = (i < NN) ? cnt[i] : 0;
  int x = v;
  sh[tid] = x; __syncthreads();
  for (int off = 1; off < 1024; off <<= 1){
    int y = (tid >= off) ? sh[tid - off] : 0;
    __syncthreads();
    x += y; sh[tid] = x; __syncthreads();
  }
  if (i < NN) excl[i] = x - v;
  if (tid == 1023) bsum[blockIdx.x] = x;
}

__global__ void k_scanB(int* __restrict__ bsum, int nb){
  if (threadIdx.x == 0){
    int run = 0;
    for (int b = 0; b < nb; ++b){ int t = bsum[b]; bsum[b] = run; run += t; }
  }
}

__global__ void k_scanC(const int* __restrict__ excl, const int* __restrict__ bsum,
                        int* __restrict__ rowptr, int* __restrict__ cursor){
  int i = blockIdx.x*1024 + threadIdx.x;
  if (i < NN){
    int v = excl[i] + bsum[blockIdx.x];
    rowptr[i] = v; cursor[i] = v;
  }
  if (i == 0) rowptr[NN] = EE + NN;
}

__global__ void k_scatter(const int* __restrict__ ei, int* __restrict__ cursor,
                          int* __restrict__ csr){
  int i = blockIdx.x*256 + threadIdx.x;
  if (i < EE){
    int d = ei[EE + i];
    int p = atomicAdd(&cursor[d], 1);
    csr[p] = ei[i];
  } else if (i < EE + NN){
    int v = i - EE;
    int p = atomicAdd(&cursor[v], 1);
    csr[p] = v;
  }
}

// ---------------- weight preprocessing ----------------
__global__ void k_prep(const float* __restrict__ W1, const float* __restrict__ as1,
                       const float* __restrict__ ad1,
                       const float* __restrict__ W2, const float* __restrict__ as2,
                       const float* __restrict__ ad2,
                       const float* __restrict__ cw1, const float* __restrict__ cw2,
                       const float* __restrict__ lw1,
                       float* __restrict__ Was1, float* __restrict__ Wad1,
                       float* __restrict__ Wat2, float* __restrict__ Wb,
                       float4* __restrict__ wq1, float4* __restrict__ wq2,
                       float* __restrict__ lw1t){
  int tid = threadIdx.x;          // 256
  int k = tid >> 2, h = tid & 3;
  float s1 = 0.f, d1 = 0.f, s2 = 0.f, d2 = 0.f;
  for (int c = 0; c < 16; ++c){
    float w = W1[k*64 + h*16 + c];
    s1 += w * as1[h*16 + c];
    d1 += w * ad1[h*16 + c];
  }
  for (int c = 0; c < 64; ++c){
    float w = W2[k*256 + h*64 + c];
    s2 += w * as2[h*64 + c];
    d2 += w * ad2[h*64 + c];
  }
  Was1[k*4+h] = s1; Wad1[k*4+h] = d1;
  Wat2[k*8 + h] = s2; Wat2[k*8 + 4 + h] = d2;
  for (int idx = tid; idx < 256*64; idx += 256){
    int kf = idx >> 6, c = idx & 63;
    int hh = kf >> 6, kk = kf & 63;
    Wb[idx] = W2[kk*256 + hh*64 + c];
  }
  // conv weights [o][i][k] -> float4 at [o*64+i]
  for (int idx = tid; idx < 64*64; idx += 256){
    int o = idx >> 6, i = idx & 63;
    wq1[idx] = make_float4(cw1[o*192+i*3], cw1[o*192+i*3+1], cw1[o*192+i*3+2], 0.f);
    wq2[idx] = make_float4(cw2[o*192+i*3], cw2[o*192+i*3+1], cw2[o*192+i*3+2], 0.f);
  }
  // lw1 [k][32] -> lw1t [j][k]
  for (int idx = tid; idx < 32*64; idx += 256){
    int j = idx >> 6, kk = idx & 63;
    lw1t[idx] = lw1[kk*32 + j];
  }
}

// ---------------- layer-1 GEMM (N x 64 @ 64 x 64) + fused attention epilogue ----
__global__ __launch_bounds__(256) void k_gemm_att1(const float* __restrict__ A,
                            const float* __restrict__ W,
                            const float* __restrict__ Was, const float* __restrict__ Wad,
                            float* __restrict__ Xl, float* __restrict__ a_src,
                            float* __restrict__ a_dst){
  __shared__ float At[64][16];
  int tid = threadIdx.x;
  int r0 = blockIdx.x * 16;
  {
    const float4* A4 = (const float4*)(A + (size_t)r0*64);
    float4 v = A4[tid];
    int r = tid >> 4, k4 = (tid & 15) << 2;
    At[k4+0][r] = v.x; At[k4+1][r] = v.y;
    At[k4+2][r] = v.z; At[k4+3][r] = v.w;
  }
  __syncthreads();
  int col = tid & 63;
  int rbase = (tid >> 6) << 2;
  float acc0=0.f, acc1=0.f, acc2=0.f, acc3=0.f;
  for (int k = 0; k < 64; ++k){
    float w = W[k*64 + col];
    float4 a4 = *(const float4*)&At[k][rbase];
    acc0 += a4.x*w; acc1 += a4.y*w; acc2 += a4.z*w; acc3 += a4.w*w;
  }
  Xl[(size_t)(r0+rbase+0)*64 + col] = acc0;
  Xl[(size_t)(r0+rbase+1)*64 + col] = acc1;
  Xl[(size_t)(r0+rbase+2)*64 + col] = acc2;
  Xl[(size_t)(r0+rbase+3)*64 + col] = acc3;
  if (tid < 128){
    int r = tid >> 3, jx = tid & 7;
    int h = jx & 3;
    const float* Wv = (jx < 4) ? Was : Wad;
    float a = 0.f;
    for (int k = 0; k < 64; ++k) a += At[k][r] * Wv[k*4 + h];
    if (jx < 4) a_src[(r0 + r)*4 + h] = a;
    else        a_dst[(r0 + r)*4 + h] = a;
  }
}

// ---------------- layer 1 aggregation + fused layer-2 attention coefficients ----
__global__ void k_agg1(const float* __restrict__ xl, const float* __restrict__ a_src,
                       const float* __restrict__ a_dst, const float* __restrict__ b1,
                       const float* __restrict__ Wat2,
                       const int* __restrict__ rowptr, const int* __restrict__ csr,
                       float* __restrict__ h1,
                       float* __restrict__ a_src2, float* __restrict__ a_dst2){
  int lane = threadIdx.x & 63;
  int wid  = threadIdx.x >> 6;
  int n = blockIdx.x*4 + wid;
  int h = lane >> 4;
  float ad = a_dst[n*4 + h];
  int rs = rowptr[n], re = rowptr[n+1];
  float s = 0.f, acc = 0.f;
  int j = rs;
  for (; j + 4 <= re; j += 4){
    int sn0=csr[j], sn1=csr[j+1], sn2=csr[j+2], sn3=csr[j+3];
    float e0=a_src[sn0*4+h], e1=a_src[sn1*4+h], e2=a_src[sn2*4+h], e3=a_src[sn3*4+h];
    float x0=xl[(size_t)sn0*64+lane], x1=xl[(size_t)sn1*64+lane];
    float x2=xl[(size_t)sn2*64+lane], x3=xl[(size_t)sn3*64+lane];
    float p0=__expf(lrelu(e0+ad)), p1=__expf(lrelu(e1+ad));
    float p2=__expf(lrelu(e2+ad)), p3=__expf(lrelu(e3+ad));
    s += p0; acc += p0*x0;
    s += p1; acc += p1*x1;
    s += p2; acc += p2*x2;
    s += p3; acc += p3*x3;
  }
  for (; j < re; ++j){
    int sn = csr[j];
    float p = __expf(lrelu(a_src[sn*4+h] + ad));
    float x = xl[(size_t)sn*64 + lane];
    s += p; acc += p*x;
  }
  float hv = eluf(acc/(s + 1e-16f) + b1[lane]);
  h1[(size_t)n*64 + lane] = hv;
  // layer-2 attention coefficients: p[j] = sum_k h1[n][k]*Wat2[k][j]
  float4 wA = ((const float4*)Wat2)[lane*2];
  float4 wB = ((const float4*)Wat2)[lane*2 + 1];
  float p[8];
  p[0]=hv*wA.x; p[1]=hv*wA.y; p[2]=hv*wA.z; p[3]=hv*wA.w;
  p[4]=hv*wB.x; p[5]=hv*wB.y; p[6]=hv*wB.z; p[7]=hv*wB.w;
#pragma unroll
  for (int off = 32; off >= 1; off >>= 1){
#pragma unroll
    for (int q = 0; q < 8; ++q) p[q] += __shfl_xor(p[q], off);
  }
  if (lane == 0){
    ((float4*)a_src2)[n] = make_float4(p[0],p[1],p[2],p[3]);
    ((float4*)a_dst2)[n] = make_float4(p[4],p[5],p[6],p[7]);
  }
}

// ---------------- layer 2 aggregation over h1 (commuted past W2) ----------------
__global__ void k_agg2(const float* __restrict__ h1, const float* __restrict__ a_src,
                       const float* __restrict__ a_dst,
                       const int* __restrict__ rowptr, const int* __restrict__ csr,
                       float* __restrict__ agg){
  int lane = threadIdx.x & 63;
  int wid  = threadIdx.x >> 6;
  int n = blockIdx.x*4 + wid;
  float4 ad = ((const float4*)a_dst)[n];
  int rs = rowptr[n], re = rowptr[n+1];
  float s0=0.f,s1=0.f,s2=0.f,s3=0.f;
  float g0=0.f,g1=0.f,g2=0.f,g3=0.f;
  int j = rs;
  for (; j + 4 <= re; j += 4){
    int sa=csr[j], sb=csr[j+1], sc=csr[j+2], sd=csr[j+3];
    float4 ea = ((const float4*)a_src)[sa];
    float4 eb = ((const float4*)a_src)[sb];
    float4 ec = ((const float4*)a_src)[sc];
    float4 ed = ((const float4*)a_src)[sd];
    float xa = h1[(size_t)sa*64 + lane];
    float xb = h1[(size_t)sb*64 + lane];
    float xc = h1[(size_t)sc*64 + lane];
    float xd = h1[(size_t)sd*64 + lane];
    float pa0=__expf(lrelu(ea.x+ad.x)), pa1=__expf(lrelu(ea.y+ad.y));
    float pa2=__expf(lrelu(ea.z+ad.z)), pa3=__expf(lrelu(ea.w+ad.w));
    float pb0=__expf(lrelu(eb.x+ad.x)), pb1=__expf(lrelu(eb.y+ad.y));
    float pb2=__expf(lrelu(eb.z+ad.z)), pb3=__expf(lrelu(eb.w+ad.w));
    float pc0=__expf(lrelu(ec.x+ad.x)), pc1=__expf(lrelu(ec.y+ad.y));
    float pc2=__expf(lrelu(ec.z+ad.z)), pc3=__expf(lrelu(ec.w+ad.w));
    float pd0=__expf(lrelu(ed.x+ad.x)), pd1=__expf(lrelu(ed.y+ad.y));
    float pd2=__expf(lrelu(ed.z+ad.z)), pd3=__expf(lrelu(ed.w+ad.w));
    s0 += pa0+pb0+pc0+pd0; g0 += pa0*xa + pb0*xb + pc0*xc + pd0*xd;
    s1 += pa1+pb1+pc1+pd1; g1 += pa1*xa + pb1*xb + pc1*xc + pd1*xd;
    s2 += pa2+pb2+pc2+pd2; g2 += pa2*xa + pb2*xb + pc2*xc + pd2*xd;
    s3 += pa3+pb3+pc3+pd3; g3 += pa3*xa + pb3*xb + pc3*xc + pd3*xd;
  }
  for (; j < re; ++j){
    int sn = csr[j];
    float4 ev = ((const float4*)a_src)[sn];
    float x = h1[(size_t)sn*64 + lane];
    float p0=__expf(lrelu(ev.x+ad.x)), p1=__expf(lrelu(ev.y+ad.y));
    float p2=__expf(lrelu(ev.z+ad.z)), p3=__expf(lrelu(ev.w+ad.w));
    s0 += p0; g0 += p0*x;
    s1 += p1; g1 += p1*x;
    s2 += p2; g2 += p2*x;
    s3 += p3; g3 += p3*x;
  }
  size_t base = (size_t)n*256 + lane;
  agg[base      ] = g0/(s0 + 1e-16f);
  agg[base +  64] = g1/(s1 + 1e-16f);
  agg[base + 128] = g2/(s2 + 1e-16f);
  agg[base + 192] = g3/(s3 + 1e-16f);
}

// ---------------- layer-2 output GEMM: [N,256]@Wb[256,64] via LDS A^T tile -------
__global__ __launch_bounds__(256) void k_out2(const float* __restrict__ agg,
                                              const float* __restrict__ Wb,
                                              const float* __restrict__ b2,
                                              float* __restrict__ ht){
  __shared__ float AtF[256*20];    // At[k][r], stride 20 (16B-aligned, bank-spread)
  int tid = threadIdx.x;
  int r0 = blockIdx.x * 16;
  const float4* A4 = (const float4*)(agg + (size_t)r0*256);
#pragma unroll
  for (int jj = 0; jj < 4; ++jj){
    int m = tid + 256*jj;
    float4 v = A4[m];
    int row = m >> 6, k0 = (m & 63) << 2;
    AtF[(k0+0)*20 + row] = v.x;
    AtF[(k0+1)*20 + row] = v.y;
    AtF[(k0+2)*20 + row] = v.z;
    AtF[(k0+3)*20 + row] = v.w;
  }
  __syncthreads();
  int col = tid & 63;
  int rbase = (tid >> 6) << 2;
  float acc0=0.f, acc1=0.f, acc2=0.f, acc3=0.f;
  for (int k = 0; k < 256; ++k){
    float w = Wb[(size_t)k*64 + col];
    float4 a4 = *(const float4*)&AtF[k*20 + rbase];
    acc0 += a4.x*w; acc1 += a4.y*w; acc2 += a4.z*w; acc3 += a4.w*w;
  }
  float bb = b2[col];
  ht[(size_t)(r0+rbase+0)*64 + col] = eluf(0.25f*acc0 + bb);
  ht[(size_t)(r0+rbase+1)*64 + col] = eluf(0.25f*acc1 + bb);
  ht[(size_t)(r0+rbase+2)*64 + col] = eluf(0.25f*acc2 + bb);
  ht[(size_t)(r0+rbase+3)*64 + col] = eluf(0.25f*acc3 + bb);
}

// ---------------- transpose htb[t][n][ch] -> Xq[ch][8t][n] (t 0,7 zero pad) -----
__global__ __launch_bounds__(256) void k_xposeQ(const float* __restrict__ htb,
                                                float* __restrict__ Xq){
  __shared__ float T[64][65];
  int tid = threadIdx.x;
  int q = tid >> 6, lane = tid & 63;
  int n0 = blockIdx.x * 64;
  int nw = n0 + lane;
  bool ok = (nw < NN);
  // zero pad rows t=0,7
  for (int jj = 0; jj < 16; ++jj){
    int ch = q*16 + jj;
    if (ok){
      Xq[((size_t)ch*8 + 0)*NN + nw] = 0.f;
      Xq[((size_t)ch*8 + 7)*NN + nw] = 0.f;
    }
  }
  for (int t = 0; t < 6; ++t){
    for (int jj = 0; jj < 16; ++jj){
      int nn = q*16 + jj;
      int nsrc = n0 + nn; if (nsrc >= NN) nsrc = NN-1;
      T[nn][lane] = htb[((size_t)t*NN + nsrc)*64 + lane];
    }
    __syncthreads();
    if (ok){
      for (int jj = 0; jj < 16; ++jj){
        int ch = q*16 + jj;
        Xq[((size_t)ch*8 + t + 1)*NN + nw] = T[lane][ch];
      }
    }
    __syncthreads();
  }
}

// ---------------- temporal convs + MLP: lane = node, o split across waves -------
__global__ __launch_bounds__(256) void k_convQ(
    const float* __restrict__ Xq, float* __restrict__ C1,
    const float4* __restrict__ wq1, const float* __restrict__ cb1,
    const float* __restrict__ g1,   const float* __restrict__ be1,
    const float4* __restrict__ wq2, const float* __restrict__ cb2,
    const float* __restrict__ g2,   const float* __restrict__ be2,
    const float* __restrict__ lw1t, const float* __restrict__ lb1,
    const float* __restrict__ lw2,  const float* __restrict__ lb2,
    float* __restrict__ out){
  __shared__ float pool_lds[64][65];
  __shared__ float outp[4][64];
  int lane = threadIdx.x & 63;
  int w = __builtin_amdgcn_readfirstlane(threadIdx.x >> 6);
  int n0 = blockIdx.x * 64;
  int n = n0 + lane;
  int nc = (n < NN) ? n : (NN-1);
  bool ok = (n < NN);

  // ---- conv1: this wave computes o in [w*16, w*16+16) for 64 nodes ----
#pragma unroll
  for (int oc = 0; oc < 2; ++oc){
    int ob = w*16 + oc*8;
    float acc[8][6];
#pragma unroll
    for (int o = 0; o < 8; ++o){
      float c = cb1[ob+o];
#pragma unroll
      for (int t = 0; t < 6; ++t) acc[o][t] = c;
    }
    for (int i = 0; i < 64; ++i){
      const float* xp = Xq + (size_t)i*8*NN + nc;
      float x0 = xp[0*NN], x1 = xp[1*NN], x2 = xp[2*NN], x3 = xp[3*NN];
      float x4 = xp[4*NN], x5 = xp[5*NN], x6 = xp[6*NN], x7 = xp[7*NN];
#pragma unroll
      for (int o = 0; o < 8; ++o){
        float4 wv = wq1[(ob+o)*64 + i];
        acc[o][0] += wv.x*x0 + wv.y*x1 + wv.z*x2;
        acc[o][1] += wv.x*x1 + wv.y*x2 + wv.z*x3;
        acc[o][2] += wv.x*x2 + wv.y*x3 + wv.z*x4;
        acc[o][3] += wv.x*x3 + wv.y*x4 + wv.z*x5;
        acc[o][4] += wv.x*x4 + wv.y*x5 + wv.z*x6;
        acc[o][5] += wv.x*x5 + wv.y*x6 + wv.z*x7;
      }
    }
    if (ok){
#pragma unroll
      for (int o = 0; o < 8; ++o){
        float bns = g1[ob+o]*rsqrtf(1.f + 1e-5f), be = be1[ob+o];
        float* cp = C1 + (size_t)(ob+o)*8*NN + n;
        cp[0*NN] = 0.f; cp[7*NN] = 0.f;
#pragma unroll
        for (int t = 0; t < 6; ++t) cp[(t+1)*NN] = fmaxf(acc[o][t]*bns + be, 0.f);
      }
    }
  }
  __syncthreads();
  // ---- conv2 + pool ----
#pragma unroll
  for (int oc = 0; oc < 2; ++oc){
    int ob = w*16 + oc*8;
    float acc[8][6];
#pragma unroll
    for (int o = 0; o < 8; ++o){
      float c = cb2[ob+o];
#pragma unroll
      for (int t = 0; t < 6; ++t) acc[o][t] = c;
    }
    for (int i = 0; i < 64; ++i){
      const float* xp = C1 + (size_t)i*8*NN + nc;
      float x0 = xp[0*NN], x1 = xp[1*NN], x2 = xp[2*NN], x3 = xp[3*NN];
      float x4 = xp[4*NN], x5 = xp[5*NN], x6 = xp[6*NN], x7 = xp[7*NN];
#pragma unroll
      for (int o = 0; o < 8; ++o){
        float4 wv = wq2[(ob+o)*64 + i];
        acc[o][0] += wv.x*x0 + wv.y*x1 + wv.z*x2;
        acc[o][1] += wv.x*x1 + wv.y*x2 + wv.z*x3;
        acc[o][2] += wv.x*x2 + wv.y*x3 + wv.z*x4;
        acc[o][3] += wv.x*x3 + wv.y*x4 + wv.z*x5;
        acc[o][4] += wv.x*x4 + wv.y*x5 + wv.z*x6;
        acc[o][5] += wv.x*x5 + wv.y*x6 + wv.z*x7;
      }
    }
#pragma unroll
    for (int o = 0; o < 8; ++o){
      float bns = g2[ob+o]*rsqrtf(1.f + 1e-5f), be = be2[ob+o];
      float pooled = 0.f;
#pragma unroll
      for (int t = 0; t < 6; ++t) pooled += fmaxf(acc[o][t]*bns + be, 0.f);
      pool_lds[ob+o][lane] = pooled*(1.f/6.f);
    }
  }
  __syncthreads();
  // ---- MLP: wave w computes hidden j in [w*8, w*8+8) for all 64 nodes ----
  {
    float hacc[8];
#pragma unroll
    for (int jj = 0; jj < 8; ++jj) hacc[jj] = 0.f;
    for (int k = 0; k < 64; ++k){
      float pk = pool_lds[k][lane];
#pragma unroll
      for (int jj = 0; jj < 8; ++jj)
        hacc[jj] += pk * lw1t[(w*8+jj)*64 + k];
    }
    float po = 0.f;
#pragma unroll
    for (int jj = 0; jj < 8; ++jj)
      po += fmaxf(hacc[jj] + lb1[w*8+jj], 0.f) * lw2[w*8+jj];
    outp[w][lane] = po;
  }
  __syncthreads();
  if (w == 0 && ok)
    out[n] = outp[0][lane] + outp[1][lane] + outp[2][lane] + outp[3][lane] + lb2[0];
}

// ---------------- launch ----------------
extern "C" void kernel_launch(void* const* d_in, const int* in_sizes, int n_in,
                              void* d_out, int out_size, void* d_ws, size_t ws_size,
                              hipStream_t stream) {
  const float* x_seq = (const float*)d_in[0];
  const int*   ei    = (const int*)  d_in[1];
  const float* W1  = (const float*)d_in[2];
  const float* as1 = (const float*)d_in[3];
  const float* ad1 = (const float*)d_in[4];
  const float* b1  = (const float*)d_in[5];
  const float* W2  = (const float*)d_in[6];
  const float* as2 = (const float*)d_in[7];
  const float* ad2 = (const float*)d_in[8];
  const float* b2  = (const float*)d_in[9];
  const float* cw1 = (const float*)d_in[10];
  const float* cb1 = (const float*)d_in[11];
  const float* g1  = (const float*)d_in[12];
  const float* be1 = (const float*)d_in[13];
  const float* cw2 = (const float*)d_in[14];
  const float* cb2 = (const float*)d_in[15];
  const float* g2  = (const float*)d_in[16];
  const float* be2 = (const float*)d_in[17];
  const float* lw1 = (const float*)d_in[18];
  const float* lb1 = (const float*)d_in[19];
  const float* lw2 = (const float*)d_in[20];
  const float* lb2 = (const float*)d_in[21];
  float* out = (float*)d_out;

  const size_t QSZ = (size_t)64*8*NN*sizeof(float);   // 102.4 MB
  char* wp = (char*)d_ws;
  auto alloc = [&](size_t bytes) -> char* {
    char* p = wp; wp += (bytes + 255) & ~(size_t)255; return p;
  };
  // region 1: GAT scratch (lives during t-loop) UNION Xq (lives after)
  char* region1 = alloc(QSZ);
  // small persistent weights
  float* Was1 = (float*)alloc(256*sizeof(float));
  float* Wad1 = (float*)alloc(256*sizeof(float));
  float* Wat2 = (float*)alloc(64*8*sizeof(float));
  float* Wb   = (float*)alloc(256*64*sizeof(float));
  float4* wq1 = (float4*)alloc(64*64*sizeof(float4));
  float4* wq2 = (float4*)alloc(64*64*sizeof(float4));
  float* lw1t = (float*)alloc(32*64*sizeof(float));
  // region 2: htb (lives until xposeQ) UNION C1 (lives after)
  char* region2 = alloc(QSZ);

  // GAT scratch carved out of region1
  char* sp = region1;
  auto salloc = [&](size_t bytes) -> char* {
    char* p = sp; sp += (bytes + 255) & ~(size_t)255; return p;
  };
  int*   counts = (int*)  salloc(NN*sizeof(int));
  int*   excl   = (int*)  salloc(NN*sizeof(int));
  int*   bsum   = (int*)  salloc(64*sizeof(int));
  int*   rowptr = (int*)  salloc((NN+1)*sizeof(int));
  int*   cursor = (int*)  salloc(NN*sizeof(int));
  int*   csr    = (int*)  salloc((size_t)(EE+NN)*sizeof(int));
  float* a_src1 = (float*)salloc((size_t)NN*4*sizeof(float));
  float* a_dst1 = (float*)salloc((size_t)NN*4*sizeof(float));
  float* a_src2 = (float*)salloc((size_t)NN*4*sizeof(float));
  float* a_dst2 = (float*)salloc((size_t)NN*4*sizeof(float));
  float* h1     = (float*)salloc((size_t)NN*64*sizeof(float));
  float* agg    = (float*)salloc((size_t)NN*256*sizeof(float));
  float* xl1    = agg;                 // layer-1 features (dead before agg write)
  float* Xq     = (float*)region1;     // aliases GAT scratch, used after t-loop
  float* htb    = (float*)region2;
  float* C1     = (float*)region2;     // aliases htb, used after xposeQ

  const int NBSCAN = (NN + 1023)/1024;   // 49
  k_init_counts<<<(NN+255)/256, 256, 0, stream>>>(counts);
  k_hist<<<(EE+255)/256, 256, 0, stream>>>(ei + EE, counts);
  k_scanA<<<NBSCAN, 1024, 0, stream>>>(counts, excl, bsum);
  k_scanB<<<1, 64, 0, stream>>>(bsum, NBSCAN);
  k_scanC<<<NBSCAN, 1024, 0, stream>>>(excl, bsum, rowptr, cursor);
  k_scatter<<<(EE+NN+255)/256, 256, 0, stream>>>(ei, cursor, csr);
  k_prep<<<1, 256, 0, stream>>>(W1, as1, ad1, W2, as2, ad2, cw1, cw2, lw1,
                                Was1, Wad1, Wat2, Wb, wq1, wq2, lw1t);

  for (int t = 0; t < TT; ++t){
    const float* xt = x_seq + (size_t)t*NN*64;
    k_gemm_att1<<<NN/16, 256, 0, stream>>>(xt, W1, Was1, Wad1, xl1, a_src1, a_dst1);
    k_agg1<<<NN/4, 256, 0, stream>>>(xl1, a_src1, a_dst1, b1, Wat2, rowptr, csr,
                                     h1, a_src2, a_dst2);
    k_agg2<<<NN/4, 256, 0, stream>>>(h1, a_src2, a_dst2, rowptr, csr, agg);
    k_out2<<<NN/16, 256, 0, stream>>>(agg, Wb, b2, htb + (size_t)t*NN*64);
  }
  const int NB64 = (NN + 63)/64;   // 782
  k_xposeQ<<<NB64, 256, 0, stream>>>(htb, Xq);
  k_convQ<<<NB64, 256, 0, stream>>>(Xq, C1, wq1, cb1, g1, be1, wq2, cb2, g2, be2,
                                    lw1t, lb1, lw2, lb2, out);
}